// Round 7
// baseline (1731.075 us; speedup 1.0000x reference)
//
#include <hip/hip_runtime.h>
#include <hip/hip_bf16.h>
#include <math.h>

// MidBlock: ResNet(conv3x3,GN/SiLU x2) -> Attention(HW=1024,C=512) -> ResNet
// All heavy math on MFMA via split-bf16 (x = hi + lo bf16; D = ah*bh + ah*bl
// + al*bh, fp32 accumulate). Measured r6: passed, absmax 0.031, 1502us total;
// conv = 59% of time at MfmaUtil 46%, Occupancy 21% (2 blocks/CU). This rev:
// conv blocks split 128oc -> 64oc (grid 512 -> 1024, 4 blocks/CU) for TLP.

#define BATCH 16
#define CCH   512
#define HH    32
#define WW    32
#define HWP   1024
#define NGRP  32
#define CPG   16
#define GN_EPS 1e-6f

typedef __attribute__((ext_vector_type(8))) short bf16x8;   // 8 bf16 (4 VGPR)
typedef __attribute__((ext_vector_type(4))) short s16x4;    // 8B store
typedef __attribute__((ext_vector_type(4))) float f32x4;    // MFMA acc

static __device__ __forceinline__ void split_bf16(float v, short& hi, short& lo) {
    __hip_bfloat16 h = __float2bfloat16(v);
    hi = *reinterpret_cast<short*>(&h);
    __hip_bfloat16 l = __float2bfloat16(v - __bfloat162float(h));
    lo = *reinterpret_cast<short*>(&l);
}

// ---------------------------------------------------------------------------
// xsplit: x[b][c][32][32] fp32 -> XThi/XTlo[b][h][w][c] bf16 (ic-fastest).
// ---------------------------------------------------------------------------
__global__ __launch_bounds__(256) void xsplit_kernel(
    const float* __restrict__ x, short* __restrict__ XThi, short* __restrict__ XTlo)
{
    __shared__ float lx[256][34];
    const int t = threadIdx.x;
    const int h = blockIdx.x, b = blockIdx.y;
    for (int half = 0; half < 2; ++half) {
        __syncthreads();
#pragma unroll
        for (int it = 0; it < 8; ++it) {
            const int i = t + it * 256;
            const int c = i >> 3, q = i & 7;
            *(float4*)&lx[c][q * 4] =
                *(const float4*)&x[((long)(b * CCH + half * 256 + c)) * HWP + h * WW + q * 4];
        }
        __syncthreads();
        const int wcol = t >> 3;            // w coordinate 0..31
        const int cc   = (t & 7) * 32;      // 32-channel chunk
        short hi[32], lo[32];
#pragma unroll
        for (int k = 0; k < 32; ++k)
            split_bf16(lx[cc + k][wcol], hi[k], lo[k]);
        const long base = (((long)b * 32 + h) * 32 + wcol) * 512 + half * 256 + cc;
#pragma unroll
        for (int c4 = 0; c4 < 4; ++c4) {
            bf16x8 vh, vl;
#pragma unroll
            for (int j = 0; j < 8; ++j) { vh[j] = hi[c4 * 8 + j]; vl[j] = lo[c4 * 8 + j]; }
            *(bf16x8*)&XThi[base + c4 * 8] = vh;
            *(bf16x8*)&XTlo[base + c4 * 8] = vl;
        }
    }
}

// ---------------------------------------------------------------------------
// wprep: W[oc][ic][3][3] fp32 -> W2hi/W2lo[tap][icb][oc][ici] (ici fastest).
// ---------------------------------------------------------------------------
__global__ __launch_bounds__(256) void wprep_kernel(
    const float* __restrict__ w, short* __restrict__ W2hi, short* __restrict__ W2lo)
{
    __shared__ float lw[4608];
    const int t = threadIdx.x;
    const int oc = blockIdx.x;
    for (int i = t; i < 4608; i += 256) lw[i] = w[(long)oc * 4608 + i];
    __syncthreads();
    if (t < 144) {
        const int tap = t % 9, icb = t / 9;
        short hi[32], lo[32];
#pragma unroll
        for (int k = 0; k < 32; ++k)
            split_bf16(lw[(icb * 32 + k) * 9 + tap], hi[k], lo[k]);
        const long base = ((long)(tap * 16 + icb) * 512 + oc) * 32;
#pragma unroll
        for (int c4 = 0; c4 < 4; ++c4) {
            bf16x8 vh, vl;
#pragma unroll
            for (int j = 0; j < 8; ++j) { vh[j] = hi[c4 * 8 + j]; vl[j] = lo[c4 * 8 + j]; }
            *(bf16x8*)&W2hi[base + c4 * 8] = vh;
            *(bf16x8*)&W2lo[base + c4 * 8] = vl;
        }
    }
}

// ---------------------------------------------------------------------------
// conv3x3 split-bf16 MFMA. Block tile: 128 px (4 rows) x 64 oc; grid
// (8 px, 8 oc, 16 b) = 1024 blocks -> 4 blocks/CU (16 waves/CU; LDS 32KB/block
// caps at 5). 4 waves = 2(wo) x 2(wp); per wave 32oc x 64px = 2x4 frags of
// 16x16x32. A=weights(m=oc), B=pixels(n=px). Taps via shifted reads of a
// [6][34][40] halo tile.
// ---------------------------------------------------------------------------
__global__ __launch_bounds__(256) void conv3x3_mfma(
    const short* __restrict__ XThi, const short* __restrict__ XTlo,
    const short* __restrict__ W2hi, const short* __restrict__ W2lo,
    const float* __restrict__ bias, float* __restrict__ y)
{
    __shared__ __align__(16) short Ah[6][34][40];
    __shared__ __align__(16) short Al[6][34][40];
    const int t = threadIdx.x;
    const int lane = t & 63, lg = lane >> 4, li = lane & 15;
    const int wv = t >> 6, wo = wv & 1, wp = wv >> 1;
    const int pt = blockIdx.x, ot = blockIdx.y, b = blockIdx.z;
    const int r0 = pt * 4;

    f32x4 acc[2][4];
#pragma unroll
    for (int i = 0; i < 2; ++i)
#pragma unroll
        for (int j = 0; j < 4; ++j) { f32x4 z = {0.f, 0.f, 0.f, 0.f}; acc[i][j] = z; }

    for (int icb = 0; icb < 16; ++icb) {
        __syncthreads();
        for (int i = t; i < 1632; i += 256) {          // 2 arrays x 816 chunks
            const int arr = (i >= 816) ? 1 : 0;
            const int pos = arr ? i - 816 : i;
            const int ch = pos & 3;
            const int xi = (pos >> 2) % 34;
            const int rs = (pos >> 2) / 34;
            const int g = r0 - 1 + rs, xg = xi - 1;
            bf16x8 v;
#pragma unroll
            for (int j = 0; j < 8; ++j) v[j] = 0;
            if (g >= 0 && g < HH && xg >= 0 && xg < WW) {
                const short* src = arr ? XTlo : XThi;
                v = *(const bf16x8*)&src[(((long)b * 32 + g) * 32 + xg) * 512 + icb * 32 + ch * 8];
            }
            short* dst = arr ? &Al[0][0][0] : &Ah[0][0][0];
            *(bf16x8*)&dst[(rs * 34 + xi) * 40 + ch * 8] = v;
        }
        __syncthreads();

#pragma unroll
        for (int tap = 0; tap < 9; ++tap) {
            const int dy = tap / 3 - 1, dx = tap % 3 - 1;
            bf16x8 wh[2], wl[2];
#pragma unroll
            for (int of = 0; of < 2; ++of) {
                const long wb = ((long)(tap * 16 + icb) * 512
                                 + ot * 64 + wo * 32 + of * 16 + li) * 32 + lg * 8;
                wh[of] = *(const bf16x8*)&W2hi[wb];
                wl[of] = *(const bf16x8*)&W2lo[wb];
            }
#pragma unroll
            for (int pf = 0; pf < 4; ++pf) {
                const int rs = 2 * wp + (pf >> 1) + dy + 1;     // 0..5
                const int xs = (pf & 1) * 16 + li + dx + 1;     // 0..33
                const bf16x8 ph = *(const bf16x8*)&Ah[rs][xs][lg * 8];
                const bf16x8 pl = *(const bf16x8*)&Al[rs][xs][lg * 8];
#pragma unroll
                for (int of = 0; of < 2; ++of) {
                    acc[of][pf] = __builtin_amdgcn_mfma_f32_16x16x32_bf16(wh[of], ph, acc[of][pf], 0, 0, 0);
                    acc[of][pf] = __builtin_amdgcn_mfma_f32_16x16x32_bf16(wh[of], pl, acc[of][pf], 0, 0, 0);
                    acc[of][pf] = __builtin_amdgcn_mfma_f32_16x16x32_bf16(wl[of], ph, acc[of][pf], 0, 0, 0);
                }
            }
        }
    }

#pragma unroll
    for (int of = 0; of < 2; ++of) {
        const int oc = ot * 64 + wo * 32 + of * 16 + lg * 4;
        const float4 b4 = *(const float4*)&bias[oc];
#pragma unroll
        for (int pf = 0; pf < 4; ++pf) {
            const int p = wp * 64 + pf * 16 + li;
            const int row = r0 + (p >> 5), xc = p & 31;
            float* yp = &y[((long)b * CCH + oc) * HWP + row * WW + xc];
#pragma unroll
            for (int r = 0; r < 4; ++r)
                yp[(long)r * HWP] = acc[of][pf][r] + (&b4.x)[r];
        }
    }
}

// ---------------------------------------------------------------------------
// gemmM: unified split-bf16 MFMA GEMM. A=[M][K], B=[N][K] (both k-contig).
//   AM/BM: 0 = fp32 global, split during LDS staging; 1 = pre-split bf16 pair
//   OM: 0 = fp32 C[M][N], val*alpha + bias[m] + skip  (skip may alias C)
//       1 = split-bf16 pair C[M][N] + bias[m]
//       2 = split-bf16 pair TRANSPOSED C[N][M] + bias[m] (contig 8B stores)
// Tile 128x128, BK=32, 4 waves (2x2), per-wave 4x4 frags of 16x16x32.
// ---------------------------------------------------------------------------
template<int AM, int BM, int OM>
__global__ __launch_bounds__(256) void gemmM(
    const void* __restrict__ Ah_, const void* __restrict__ Al_,
    const void* __restrict__ Bh_, const void* __restrict__ Bl_,
    void* Ch_, void* Cl_,
    const float* __restrict__ bias, const float* skip,
    const int M, const int N, const int K,
    const long sA, const long sB, const long sC, const float alpha)
{
    __shared__ __align__(16) short As[2][128][40];
    __shared__ __align__(16) short Bs[2][128][40];
    const int t = threadIdx.x;
    const int li = t & 15, lg = (t >> 4) & 3;
    const int wv = t >> 6, wn = wv & 1, wm = wv >> 1;
    const int n0 = blockIdx.x * 128, m0 = blockIdx.y * 128;
    const long z = blockIdx.z;

    f32x4 acc[4][4];
#pragma unroll
    for (int i = 0; i < 4; ++i)
#pragma unroll
        for (int j = 0; j < 4; ++j) { f32x4 zz = {0.f, 0.f, 0.f, 0.f}; acc[i][j] = zz; }

    for (int k0 = 0; k0 < K; k0 += 32) {
        __syncthreads();
        // ---- stage A tile (128 m x 32 k) ----
        if (AM == 0) {
            const float* Af = (const float*)Ah_ + z * sA;
            const int m = t >> 1, kh = (t & 1) * 16;
            const float* src = &Af[(long)(m0 + m) * K + k0 + kh];
            short h[16], l[16];
#pragma unroll
            for (int q = 0; q < 4; ++q) {
                const float4 f = *(const float4*)&src[q * 4];
#pragma unroll
                for (int j = 0; j < 4; ++j) split_bf16((&f.x)[j], h[q * 4 + j], l[q * 4 + j]);
            }
            *(bf16x8*)&As[0][m][kh]     = *(bf16x8*)&h[0];
            *(bf16x8*)&As[0][m][kh + 8] = *(bf16x8*)&h[8];
            *(bf16x8*)&As[1][m][kh]     = *(bf16x8*)&l[0];
            *(bf16x8*)&As[1][m][kh + 8] = *(bf16x8*)&l[8];
        } else {
            const int m = t & 127, arr = t >> 7;
            const short* src = ((arr ? (const short*)Al_ : (const short*)Ah_) + z * sA)
                               + (long)(m0 + m) * K + k0;
#pragma unroll
            for (int q = 0; q < 4; ++q)
                *(bf16x8*)&As[arr][m][q * 8] = *(const bf16x8*)&src[q * 8];
        }
        // ---- stage B tile (128 n x 32 k) ----
        if (BM == 0) {
            const float* Bf = (const float*)Bh_ + z * sB;
            const int n = t >> 1, kh = (t & 1) * 16;
            const float* src = &Bf[(long)(n0 + n) * K + k0 + kh];
            short h[16], l[16];
#pragma unroll
            for (int q = 0; q < 4; ++q) {
                const float4 f = *(const float4*)&src[q * 4];
#pragma unroll
                for (int j = 0; j < 4; ++j) split_bf16((&f.x)[j], h[q * 4 + j], l[q * 4 + j]);
            }
            *(bf16x8*)&Bs[0][n][kh]     = *(bf16x8*)&h[0];
            *(bf16x8*)&Bs[0][n][kh + 8] = *(bf16x8*)&h[8];
            *(bf16x8*)&Bs[1][n][kh]     = *(bf16x8*)&l[0];
            *(bf16x8*)&Bs[1][n][kh + 8] = *(bf16x8*)&l[8];
        } else {
            const int n = t & 127, arr = t >> 7;
            const short* src = ((arr ? (const short*)Bl_ : (const short*)Bh_) + z * sB)
                               + (long)(n0 + n) * K + k0;
#pragma unroll
            for (int q = 0; q < 4; ++q)
                *(bf16x8*)&Bs[arr][n][q * 8] = *(const bf16x8*)&src[q * 8];
        }
        __syncthreads();

        bf16x8 ah[4], al[4], bh[4], bl[4];
#pragma unroll
        for (int f = 0; f < 4; ++f) {
            const int ra = wm * 64 + f * 16 + li;
            ah[f] = *(const bf16x8*)&As[0][ra][lg * 8];
            al[f] = *(const bf16x8*)&As[1][ra][lg * 8];
            const int rb = wn * 64 + f * 16 + li;
            bh[f] = *(const bf16x8*)&Bs[0][rb][lg * 8];
            bl[f] = *(const bf16x8*)&Bs[1][rb][lg * 8];
        }
#pragma unroll
        for (int fm = 0; fm < 4; ++fm)
#pragma unroll
            for (int fn = 0; fn < 4; ++fn) {
                acc[fm][fn] = __builtin_amdgcn_mfma_f32_16x16x32_bf16(ah[fm], bh[fn], acc[fm][fn], 0, 0, 0);
                acc[fm][fn] = __builtin_amdgcn_mfma_f32_16x16x32_bf16(ah[fm], bl[fn], acc[fm][fn], 0, 0, 0);
                acc[fm][fn] = __builtin_amdgcn_mfma_f32_16x16x32_bf16(al[fm], bh[fn], acc[fm][fn], 0, 0, 0);
            }
    }

    // ---- epilogue ----
#pragma unroll
    for (int fm = 0; fm < 4; ++fm) {
        const int gmb = m0 + wm * 64 + fm * 16 + lg * 4;
#pragma unroll
        for (int fn = 0; fn < 4; ++fn) {
            const int gn = n0 + wn * 64 + fn * 16 + li;
            if (OM == 0) {
                float* C = (float*)Ch_ + z * sC;
                const float* S = skip ? skip + z * sC : (const float*)0;
#pragma unroll
                for (int r = 0; r < 4; ++r) {
                    const int gm = gmb + r;
                    float v = acc[fm][fn][r] * alpha + (bias ? bias[gm] : 0.f);
                    const long off = (long)gm * N + gn;
                    if (S) v += S[off];
                    C[off] = v;
                }
            } else if (OM == 1) {
                short* Ch = (short*)Ch_ + z * sC;
                short* Cl = (short*)Cl_ + z * sC;
#pragma unroll
                for (int r = 0; r < 4; ++r) {
                    const int gm = gmb + r;
                    float v = acc[fm][fn][r] + (bias ? bias[gm] : 0.f);
                    short h, l; split_bf16(v, h, l);
                    const long off = (long)gm * N + gn;
                    Ch[off] = h; Cl[off] = l;
                }
            } else {
                short* Ch = (short*)Ch_ + z * sC;
                short* Cl = (short*)Cl_ + z * sC;
                s16x4 hv, lv;
#pragma unroll
                for (int r = 0; r < 4; ++r) {
                    float v = acc[fm][fn][r] + (bias ? bias[gmb + r] : 0.f);
                    short h, l; split_bf16(v, h, l);
                    hv[r] = h; lv[r] = l;
                }
                const long off = (long)gn * M + gmb;
                *(s16x4*)&Ch[off] = hv;
                *(s16x4*)&Cl[off] = lv;
            }
        }
    }
}

// ---------------------------------------------------------------------------
// GN stat helper (per-(b,group) block, 256 thr; 16384 floats in registers).
// ---------------------------------------------------------------------------
static __device__ __forceinline__ void gn_stats(
    const float* in, long base, int t, float4 (&v)[16], float& mean, float& inv)
{
    float sum = 0.f, ssq = 0.f;
#pragma unroll
    for (int i = 0; i < 16; ++i) {
        v[i] = *(const float4*)&in[base + (long)(t + 256 * i) * 4];
        sum += v[i].x + v[i].y + v[i].z + v[i].w;
        ssq += v[i].x * v[i].x + v[i].y * v[i].y + v[i].z * v[i].z + v[i].w * v[i].w;
    }
#pragma unroll
    for (int off = 32; off > 0; off >>= 1) {
        sum += __shfl_xor(sum, off);
        ssq += __shfl_xor(ssq, off);
    }
    __shared__ float redS[4], redQ[4];
    const int wid = t >> 6;
    if ((t & 63) == 0) { redS[wid] = sum; redQ[wid] = ssq; }
    __syncthreads();
    sum = redS[0] + redS[1] + redS[2] + redS[3];
    ssq = redQ[0] + redQ[1] + redQ[2] + redQ[3];
    mean = sum * (1.f / 16384.f);
    const float var = ssq * (1.f / 16384.f) - mean * mean;
    inv = rsqrtf(var + GN_EPS);
}

// GroupNorm (+SiLU/+skip), fp32 out. In-place safe. flags: bit0 silu, bit1 skip
__global__ __launch_bounds__(256) void gn_kernel(
    const float* in, const float* __restrict__ gamma,
    const float* __restrict__ beta, const float* __restrict__ skip,
    float* out, const int flags)
{
    const int t = threadIdx.x;
    const int b = blockIdx.x >> 5;
    const int g = blockIdx.x & 31;
    const long base = ((long)b * CCH + g * CPG) * HWP;
    float4 v[16];
    float mean, inv;
    gn_stats(in, base, t, v, mean, inv);
#pragma unroll
    for (int i = 0; i < 16; ++i) {
        const float ga = gamma[g * CPG + i];
        const float be = beta[g * CPG + i];
        float r[4] = { v[i].x, v[i].y, v[i].z, v[i].w };
        float4 o;
        float* op = &o.x;
#pragma unroll
        for (int c = 0; c < 4; ++c) {
            float val = (r[c] - mean) * inv * ga + be;
            if (flags & 1) val = val / (1.f + expf(-val));
            op[c] = val;
        }
        if (flags & 2) {
            const float4 s4 = *(const float4*)&skip[base + (long)(t + 256 * i) * 4];
            o.x += s4.x; o.y += s4.y; o.z += s4.z; o.w += s4.w;
        }
        *(float4*)&out[base + (long)(t + 256 * i) * 4] = o;
    }
}

// GN -> split-bf16 transposed [b][px][c] pair, optional SiLU.
template<int SILU>
__global__ __launch_bounds__(256) void gn_tsplit_k(
    const float* __restrict__ in, const float* __restrict__ gamma,
    const float* __restrict__ beta, short* __restrict__ Th, short* __restrict__ Tl)
{
    const int t = threadIdx.x;
    const int b = blockIdx.x >> 5;
    const int g = blockIdx.x & 31;
    const long base = ((long)b * CCH + g * CPG) * HWP;
    float4 v[16];
    float mean, inv;
    gn_stats(in, base, t, v, mean, inv);
#pragma unroll
    for (int cc = 0; cc < 4; ++cc) {
        short h[16], l[16];
#pragma unroll
        for (int i = 0; i < 16; ++i) {
            float val = ((&v[i].x)[cc] - mean) * inv * gamma[g * CPG + i] + beta[g * CPG + i];
            if (SILU) val = val / (1.f + expf(-val));
            split_bf16(val, h[i], l[i]);
        }
        const long o = ((long)b * HWP + (t * 4 + cc)) * CCH + g * CPG;
        *(bf16x8*)&Th[o]     = *(bf16x8*)&h[0];
        *(bf16x8*)&Th[o + 8] = *(bf16x8*)&h[8];
        *(bf16x8*)&Tl[o]     = *(bf16x8*)&l[0];
        *(bf16x8*)&Tl[o + 8] = *(bf16x8*)&l[8];
    }
}

// ---------------------------------------------------------------------------
__global__ __launch_bounds__(256) void softmax_kernel(float* __restrict__ s)
{
    float* p = s + (long)blockIdx.x * HWP;
    const int t = threadIdx.x;
    float4 v = *(float4*)&p[t * 4];
    float mx = fmaxf(fmaxf(v.x, v.y), fmaxf(v.z, v.w));
#pragma unroll
    for (int off = 32; off > 0; off >>= 1) mx = fmaxf(mx, __shfl_xor(mx, off));
    __shared__ float redm[4], reds[4];
    const int wid = t >> 6;
    if ((t & 63) == 0) redm[wid] = mx;
    __syncthreads();
    mx = fmaxf(fmaxf(redm[0], redm[1]), fmaxf(redm[2], redm[3]));
    float4 e;
    e.x = expf(v.x - mx); e.y = expf(v.y - mx);
    e.z = expf(v.z - mx); e.w = expf(v.w - mx);
    float sm = e.x + e.y + e.z + e.w;
#pragma unroll
    for (int off = 32; off > 0; off >>= 1) sm += __shfl_xor(sm, off);
    if ((t & 63) == 0) reds[wid] = sm;
    __syncthreads();
    sm = reds[0] + reds[1] + reds[2] + reds[3];
    const float r = 1.f / sm;
    e.x *= r; e.y *= r; e.z *= r; e.w *= r;
    *(float4*)&p[t * 4] = e;
}

// ---------------------------------------------------------------------------
// fp32 fallbacks (audited baseline) for the tiny-workspace tier
// ---------------------------------------------------------------------------
#define OCT 8
#define ICT 4
__global__ __launch_bounds__(256) void conv3x3_kernel(
    const float* __restrict__ x, const float* __restrict__ w,
    const float* __restrict__ bias, float* __restrict__ y)
{
    __shared__ float lds[ICT][34][36];
    const int t = threadIdx.x;
    const int oc0 = blockIdx.x * OCT;
    const int b = blockIdx.y;
    const int row = t >> 3;
    const int col = (t & 7) << 2;
    float acc[OCT][4];
#pragma unroll
    for (int o = 0; o < OCT; ++o)
#pragma unroll
        for (int p = 0; p < 4; ++p) acc[o][p] = 0.f;
    const float* xb = x + (long)b * CCH * HWP;
    for (int ic0 = 0; ic0 < CCH; ic0 += ICT) {
        __syncthreads();
#pragma unroll
        for (int pl = 0; pl < ICT; ++pl) {
            for (int i = t; i < 34 * 34; i += 256) {
                const int r = i / 34, cc = i - r * 34;
                const int gy = r - 1, gx = cc - 1;
                float v = 0.f;
                if (gy >= 0 && gy < HH && gx >= 0 && gx < WW)
                    v = xb[(long)(ic0 + pl) * HWP + gy * WW + gx];
                lds[pl][r][cc] = v;
            }
        }
        __syncthreads();
#pragma unroll
        for (int ic = 0; ic < ICT; ++ic) {
#pragma unroll
            for (int dy = 0; dy < 3; ++dy) {
                float in6[6];
#pragma unroll
                for (int j = 0; j < 6; ++j) in6[j] = lds[ic][row + dy][col + j];
#pragma unroll
                for (int dx = 0; dx < 3; ++dx) {
#pragma unroll
                    for (int o = 0; o < OCT; ++o) {
                        const float ww = w[((long)(oc0 + o) * CCH + ic0 + ic) * 9 + dy * 3 + dx];
#pragma unroll
                        for (int p = 0; p < 4; ++p)
                            acc[o][p] = fmaf(ww, in6[p + dx], acc[o][p]);
                    }
                }
            }
        }
    }
#pragma unroll
    for (int o = 0; o < OCT; ++o) {
        const float bv = bias[oc0 + o];
        float4 o4;
        o4.x = acc[o][0] + bv; o4.y = acc[o][1] + bv;
        o4.z = acc[o][2] + bv; o4.w = acc[o][3] + bv;
        *(float4*)&y[((long)(b * CCH + oc0 + o)) * HWP + row * WW + col] = o4;
    }
}

template<int AT, int BT>
__global__ __launch_bounds__(256) void gemm128(
    const float* __restrict__ A, const float* __restrict__ B,
    float* C, const float* __restrict__ bias, const float* skip,
    const int M, const int N, const int K,
    const long sA, const long sB, const long sC, const float alpha)
{
    __shared__ float as[16][132];
    __shared__ float bs[16][132];
    const int t = threadIdx.x;
    const int n0 = blockIdx.x * 128;
    const int m0 = blockIdx.y * 128;
    const float* Ap = A + (long)blockIdx.z * sA;
    const float* Bp = B + (long)blockIdx.z * sB;
    float* Cp = C + (long)blockIdx.z * sC;
    const float* Sp = skip ? skip + (long)blockIdx.z * sC : (const float*)0;
    const int tm = (t & 15) * 4;
    const int tn = (t >> 4) * 4;
    float acc[8][8];
#pragma unroll
    for (int i = 0; i < 8; ++i)
#pragma unroll
        for (int j = 0; j < 8; ++j) acc[i][j] = 0.f;
    for (int k0 = 0; k0 < K; k0 += 16) {
        __syncthreads();
        if (AT == 0) {
            const int m = t & 127;
            const int kg = (t >> 7) * 8;
            const float4 a0 = *(const float4*)&Ap[(long)(m0 + m) * K + k0 + kg];
            const float4 a1 = *(const float4*)&Ap[(long)(m0 + m) * K + k0 + kg + 4];
            as[kg + 0][m] = a0.x; as[kg + 1][m] = a0.y;
            as[kg + 2][m] = a0.z; as[kg + 3][m] = a0.w;
            as[kg + 4][m] = a1.x; as[kg + 5][m] = a1.y;
            as[kg + 6][m] = a1.z; as[kg + 7][m] = a1.w;
        } else {
            const int kk = t >> 4;
            const int mm = (t & 15) * 4;
            *(float4*)&as[kk][mm]      = *(const float4*)&Ap[(long)(k0 + kk) * M + m0 + mm];
            *(float4*)&as[kk][mm + 64] = *(const float4*)&Ap[(long)(k0 + kk) * M + m0 + mm + 64];
        }
        if (BT == 0) {
            const int kk = t >> 4;
            const int nn = (t & 15) * 4;
            *(float4*)&bs[kk][nn]      = *(const float4*)&Bp[(long)(k0 + kk) * N + n0 + nn];
            *(float4*)&bs[kk][nn + 64] = *(const float4*)&Bp[(long)(k0 + kk) * N + n0 + nn + 64];
        } else {
            const int n = t & 127;
            const int kg = (t >> 7) * 8;
            const float4 b0 = *(const float4*)&Bp[(long)(n0 + n) * K + k0 + kg];
            const float4 b1 = *(const float4*)&Bp[(long)(n0 + n) * K + k0 + kg + 4];
            bs[kg + 0][n] = b0.x; bs[kg + 1][n] = b0.y;
            bs[kg + 2][n] = b0.z; bs[kg + 3][n] = b0.w;
            bs[kg + 4][n] = b1.x; bs[kg + 5][n] = b1.y;
            bs[kg + 6][n] = b1.z; bs[kg + 7][n] = b1.w;
        }
        __syncthreads();
#pragma unroll
        for (int kk = 0; kk < 16; ++kk) {
            float av[8], bv[8];
            *(float4*)&av[0] = *(const float4*)&as[kk][tm];
            *(float4*)&av[4] = *(const float4*)&as[kk][tm + 64];
            *(float4*)&bv[0] = *(const float4*)&bs[kk][tn];
            *(float4*)&bv[4] = *(const float4*)&bs[kk][tn + 64];
#pragma unroll
            for (int i = 0; i < 8; ++i)
#pragma unroll
                for (int j = 0; j < 8; ++j)
                    acc[i][j] = fmaf(av[i], bv[j], acc[i][j]);
        }
    }
#pragma unroll
    for (int i = 0; i < 8; ++i) {
        const int ri = m0 + ((i < 4) ? (tm + i) : (64 + tm + i - 4));
        const float bv = bias ? bias[ri] : 0.f;
#pragma unroll
        for (int jh = 0; jh < 2; ++jh) {
            const int cj = n0 + ((jh == 0) ? tn : (64 + tn));
            const long off = (long)ri * N + cj;
            float4 o;
            float* op = &o.x;
#pragma unroll
            for (int j = 0; j < 4; ++j) op[j] = acc[i][jh * 4 + j] * alpha + bv;
            if (Sp) {
                const float4 s4 = *(const float4*)&Sp[off];
                o.x += s4.x; o.y += s4.y; o.z += s4.z; o.w += s4.w;
            }
            *(float4*)&Cp[off] = o;
        }
    }
}

// ---------------------------------------------------------------------------
extern "C" void kernel_launch(void* const* d_in, const int* in_sizes, int n_in,
                              void* d_out, int out_size, void* d_ws, size_t ws_size,
                              hipStream_t stream)
{
    const float* x      = (const float*)d_in[0];
    const float* r1_c1w = (const float*)d_in[1];
    const float* r1_c1b = (const float*)d_in[2];
    const float* r1_g1  = (const float*)d_in[3];
    const float* r1_b1  = (const float*)d_in[4];
    const float* r1_c2w = (const float*)d_in[5];
    const float* r1_c2b = (const float*)d_in[6];
    const float* r1_g2  = (const float*)d_in[7];
    const float* r1_b2  = (const float*)d_in[8];
    const float* a_g    = (const float*)d_in[9];
    const float* a_b    = (const float*)d_in[10];
    const float* a_qw   = (const float*)d_in[11];
    const float* a_qb   = (const float*)d_in[12];
    const float* a_kw   = (const float*)d_in[13];
    const float* a_kb   = (const float*)d_in[14];
    const float* a_vw   = (const float*)d_in[15];
    const float* a_vb   = (const float*)d_in[16];
    const float* a_pw   = (const float*)d_in[17];
    const float* a_pb   = (const float*)d_in[18];
    const float* r2_c1w = (const float*)d_in[19];
    const float* r2_c1b = (const float*)d_in[20];
    const float* r2_g1  = (const float*)d_in[21];
    const float* r2_b1  = (const float*)d_in[22];
    const float* r2_c2w = (const float*)d_in[23];
    const float* r2_c2b = (const float*)d_in[24];
    const float* r2_g2  = (const float*)d_in[25];
    const float* r2_b2  = (const float*)d_in[26];

    const long NB1   = (long)CCH * HWP;          // 524288
    const long NBUF  = (long)BATCH * NB1;        // 8.39M (33.5 MB fp32)
    const long SB1   = (long)HWP * HWP;
    const long SFULL = (long)BATCH * SB1;
    const long WSPL  = (long)9 * 16 * 512 * 32;  // 2.36M shorts per weight array

    float* ws   = (float*)d_ws;
    float* bufA = ws;
    float* bufB = ws + NBUF;
    float* out  = (float*)d_out;

    // Shared region R after bufA/bufB: conv scratch and attention scratch
    // alias each other (disjoint live ranges, verified phase order).
    short* R    = (short*)(ws + 2 * NBUF);
    short* XThi = R;                 // conv phase
    short* XTlo = R + NBUF;
    short* W2hi = R + 2 * NBUF;
    short* W2lo = W2hi + WSPL;
    short* hnTh = R;                 // attention phase (aliases XT; XT dead)
    short* hnTl = R + NBUF;
    short* Qth  = R + 2 * NBUF;      // aliases W2 + beyond (W2 dead)
    short* Qtl  = R + 3 * NBUF;
    short* Kth  = R + 4 * NBUF;
    short* Ktl  = R + 5 * NBUF;
    short* hTh  = Qth;               // Qt dead after S
    short* hTl  = Qtl;
    float* Sf   = (float*)(R + 6 * NBUF);
    short* Vh   = (short*)d_out;     // V pair lives in d_out (dead at end)
    short* Vl   = Vh + NBUF;

    // tier thresholds (bytes)
    const size_t t1 = (size_t)20 * NBUF + (size_t)4 * SFULL;           // ~235 MB
    const size_t t2 = (size_t)20 * NBUF + (size_t)4 * SB1;             // ~172 MB
    const size_t t3 = (size_t)8 * NBUF + (size_t)(2 * NBUF + 2 * WSPL) * 2
                    + (size_t)(3 * NB1 + SB1) * 4;                     // ~121 MB
    const int tier = (ws_size >= t1) ? 1 : (ws_size >= t2) ? 2
                   : (ws_size >= t3) ? 3 : 4;

    const float scale = 0.04419417382415922f;    // 512^-0.5

    const dim3 gConvM(HWP / 128, CCH / 64, BATCH);   // (8,8,16) = 1024 blocks
    const dim3 gXS(HH, BATCH);
    const dim3 gConvF(CCH / OCT, BATCH);
    const dim3 gGN(BATCH * NGRP);
    const dim3 gProj(HWP / 128, CCH / 128, BATCH);   // (8,4,16) M=512 N=1024
    const dim3 gS(HWP / 128, HWP / 128, BATCH);      // (8,8,16)
    const dim3 gSb(HWP / 128, HWP / 128, 1);
    const dim3 gPVb(HWP / 128, CCH / 128, 1);
    const dim3 g1x1b(HWP / 128, CCH / 128, 1);

    // ---- ResNet block 1 ----
    if (tier <= 3) {
        xsplit_kernel<<<gXS, 256, 0, stream>>>(x, XThi, XTlo);
        wprep_kernel<<<CCH, 256, 0, stream>>>(r1_c1w, W2hi, W2lo);
        conv3x3_mfma<<<gConvM, 256, 0, stream>>>(XThi, XTlo, W2hi, W2lo, r1_c1b, bufA);
        gn_tsplit_k<1><<<gGN, 256, 0, stream>>>(bufA, r1_g1, r1_b1, XThi, XTlo);
        wprep_kernel<<<CCH, 256, 0, stream>>>(r1_c2w, W2hi, W2lo);
        conv3x3_mfma<<<gConvM, 256, 0, stream>>>(XThi, XTlo, W2hi, W2lo, r1_c2b, bufB);
    } else {
        conv3x3_kernel<<<gConvF, 256, 0, stream>>>(x, r1_c1w, r1_c1b, bufA);
        gn_kernel<<<gGN, 256, 0, stream>>>(bufA, r1_g1, r1_b1, nullptr, bufA, 1);
        conv3x3_kernel<<<gConvF, 256, 0, stream>>>(bufA, r1_c2w, r1_c2b, bufB);
    }
    gn_kernel<<<gGN, 256, 0, stream>>>(bufB, r1_g2, r1_b2, x, bufB, 3);   // bufB = x1

    // ---- Attention ----
    if (tier <= 2) {
        gn_tsplit_k<0><<<gGN, 256, 0, stream>>>(bufB, a_g, a_b, hnTh, hnTl);
        gemmM<0, 1, 2><<<gProj, 256, 0, stream>>>(a_qw, nullptr, hnTh, hnTl,
            Qth, Qtl, a_qb, nullptr, CCH, HWP, CCH, 0, NB1, NB1, 1.f);
        gemmM<0, 1, 2><<<gProj, 256, 0, stream>>>(a_kw, nullptr, hnTh, hnTl,
            Kth, Ktl, a_kb, nullptr, CCH, HWP, CCH, 0, NB1, NB1, 1.f);
        gemmM<0, 1, 1><<<gProj, 256, 0, stream>>>(a_vw, nullptr, hnTh, hnTl,
            Vh, Vl, a_vb, nullptr, CCH, HWP, CCH, 0, NB1, NB1, 1.f);
        if (tier == 1) {
            gemmM<1, 1, 0><<<gS, 256, 0, stream>>>(Qth, Qtl, Kth, Ktl,
                Sf, nullptr, nullptr, nullptr, HWP, HWP, CCH, NB1, NB1, SB1, scale);
            softmax_kernel<<<BATCH * HWP, 256, 0, stream>>>(Sf);
            gemmM<1, 0, 2><<<gProj, 256, 0, stream>>>(Vh, Vl, Sf, nullptr,
                hTh, hTl, nullptr, nullptr, CCH, HWP, HWP, NB1, SB1, NB1, 1.f);
        } else {
            for (int b = 0; b < BATCH; ++b) {
                gemmM<1, 1, 0><<<gSb, 256, 0, stream>>>(Qth + b * NB1, Qtl + b * NB1,
                    Kth + b * NB1, Ktl + b * NB1, Sf, nullptr, nullptr, nullptr,
                    HWP, HWP, CCH, 0, 0, 0, scale);
                softmax_kernel<<<HWP, 256, 0, stream>>>(Sf);
                gemmM<1, 0, 2><<<gPVb, 256, 0, stream>>>(Vh + b * NB1, Vl + b * NB1,
                    Sf, nullptr, hTh + b * NB1, hTl + b * NB1, nullptr, nullptr,
                    CCH, HWP, HWP, 0, 0, 0, 1.f);
            }
        }
        // x2 = x1 + pw*hT + pb (in-place skip on bufB)
        gemmM<0, 1, 0><<<gProj, 256, 0, stream>>>(a_pw, nullptr, hTh, hTl,
            bufB, nullptr, a_pb, bufB, CCH, HWP, CCH, 0, NB1, NB1, 1.f);
    } else {
        gn_kernel<<<gGN, 256, 0, stream>>>(bufB, a_g, a_b, nullptr, bufA, 0);
        float* qq = (tier == 3) ? (float*)(R + 2 * NBUF + 2 * WSPL) : (float*)R;
        float* kk = qq + NB1;
        float* vv = kk + NB1;
        float* ssb = vv + NB1;
        const dim3 gQKb(HWP / 128, HWP / 128, 1);
        for (int b = 0; b < BATCH; ++b) {
            const float* hnb = bufA + (long)b * NB1;
            gemm128<0, 0><<<g1x1b, 256, 0, stream>>>(a_qw, hnb, qq, a_qb, nullptr,
                                                     CCH, HWP, CCH, 0, 0, 0, 1.f);
            gemm128<0, 0><<<g1x1b, 256, 0, stream>>>(a_kw, hnb, kk, a_kb, nullptr,
                                                     CCH, HWP, CCH, 0, 0, 0, 1.f);
            gemm128<0, 0><<<g1x1b, 256, 0, stream>>>(a_vw, hnb, vv, a_vb, nullptr,
                                                     CCH, HWP, CCH, 0, 0, 0, 1.f);
            gemm128<1, 0><<<gQKb, 256, 0, stream>>>(qq, kk, ssb, nullptr, nullptr,
                                                    HWP, HWP, CCH, 0, 0, 0, scale);
            softmax_kernel<<<HWP, 256, 0, stream>>>(ssb);
            gemm128<0, 1><<<g1x1b, 256, 0, stream>>>(vv, ssb, qq, nullptr, nullptr,
                                                     CCH, HWP, HWP, 0, 0, 0, 1.f);
            gemm128<0, 0><<<g1x1b, 256, 0, stream>>>(a_pw, qq, bufB + (long)b * NB1,
                                                     a_pb, bufB + (long)b * NB1,
                                                     CCH, HWP, CCH, 0, 0, 0, 1.f);
        }
    }

    // ---- ResNet block 2 ----
    if (tier <= 3) {
        xsplit_kernel<<<gXS, 256, 0, stream>>>(bufB, XThi, XTlo);
        wprep_kernel<<<CCH, 256, 0, stream>>>(r2_c1w, W2hi, W2lo);
        conv3x3_mfma<<<gConvM, 256, 0, stream>>>(XThi, XTlo, W2hi, W2lo, r2_c1b, bufA);
        gn_tsplit_k<1><<<gGN, 256, 0, stream>>>(bufA, r2_g1, r2_b1, XThi, XTlo);
        wprep_kernel<<<CCH, 256, 0, stream>>>(r2_c2w, W2hi, W2lo);
        conv3x3_mfma<<<gConvM, 256, 0, stream>>>(XThi, XTlo, W2hi, W2lo, r2_c2b, bufA);
    } else {
        conv3x3_kernel<<<gConvF, 256, 0, stream>>>(bufB, r2_c1w, r2_c1b, bufA);
        gn_kernel<<<gGN, 256, 0, stream>>>(bufA, r2_g1, r2_b1, nullptr, bufA, 1);
        conv3x3_kernel<<<gConvF, 256, 0, stream>>>(bufA, r2_c2w, r2_c2b, bufA);
    }
    gn_kernel<<<gGN, 256, 0, stream>>>(bufA, r2_g2, r2_b2, bufB, out, 3);
}

// Round 8
// 1443.090 us; speedup vs baseline: 1.1996x; 1.1996x over previous
//
#include <hip/hip_runtime.h>
#include <hip/hip_bf16.h>
#include <math.h>

// MidBlock: ResNet(conv3x3,GN/SiLU x2) -> Attention(HW=1024,C=512) -> ResNet
// Split-bf16 MFMA everywhere (D = ah*bh + ah*bl + al*bh, fp32 acc).
// r6: 1502us, conv 222us @ MfmaUtil 46%, occ 21% (2 blk/CU, grid-limited).
// r7 FAILED: grid split 512->1024 left occ at 24% (LDS pool is effectively
// 64KB/CU -> 32KB blocks cap at 2/CU) and doubled staging (conflicts 2x,
// FETCH +49%) -> 275us. This rev: revert to r6 geometry + T14 reg-prefetch
// pipeline in the conv K-loop (issue next-icb loads before compute, write to
// LDS after the post-compute barrier) to hide global latency under MFMA.

#define BATCH 16
#define CCH   512
#define HH    32
#define WW    32
#define HWP   1024
#define NGRP  32
#define CPG   16
#define GN_EPS 1e-6f

typedef __attribute__((ext_vector_type(8))) short bf16x8;   // 8 bf16 (4 VGPR)
typedef __attribute__((ext_vector_type(4))) short s16x4;    // 8B store
typedef __attribute__((ext_vector_type(4))) float f32x4;    // MFMA acc

static __device__ __forceinline__ void split_bf16(float v, short& hi, short& lo) {
    __hip_bfloat16 h = __float2bfloat16(v);
    hi = *reinterpret_cast<short*>(&h);
    __hip_bfloat16 l = __float2bfloat16(v - __bfloat162float(h));
    lo = *reinterpret_cast<short*>(&l);
}

// ---------------------------------------------------------------------------
// xsplit: x[b][c][32][32] fp32 -> XThi/XTlo[b][h][w][c] bf16 (ic-fastest).
// ---------------------------------------------------------------------------
__global__ __launch_bounds__(256) void xsplit_kernel(
    const float* __restrict__ x, short* __restrict__ XThi, short* __restrict__ XTlo)
{
    __shared__ float lx[256][34];
    const int t = threadIdx.x;
    const int h = blockIdx.x, b = blockIdx.y;
    for (int half = 0; half < 2; ++half) {
        __syncthreads();
#pragma unroll
        for (int it = 0; it < 8; ++it) {
            const int i = t + it * 256;
            const int c = i >> 3, q = i & 7;
            *(float4*)&lx[c][q * 4] =
                *(const float4*)&x[((long)(b * CCH + half * 256 + c)) * HWP + h * WW + q * 4];
        }
        __syncthreads();
        const int wcol = t >> 3;            // w coordinate 0..31
        const int cc   = (t & 7) * 32;      // 32-channel chunk
        short hi[32], lo[32];
#pragma unroll
        for (int k = 0; k < 32; ++k)
            split_bf16(lx[cc + k][wcol], hi[k], lo[k]);
        const long base = (((long)b * 32 + h) * 32 + wcol) * 512 + half * 256 + cc;
#pragma unroll
        for (int c4 = 0; c4 < 4; ++c4) {
            bf16x8 vh, vl;
#pragma unroll
            for (int j = 0; j < 8; ++j) { vh[j] = hi[c4 * 8 + j]; vl[j] = lo[c4 * 8 + j]; }
            *(bf16x8*)&XThi[base + c4 * 8] = vh;
            *(bf16x8*)&XTlo[base + c4 * 8] = vl;
        }
    }
}

// ---------------------------------------------------------------------------
// wprep: W[oc][ic][3][3] fp32 -> W2hi/W2lo[tap][icb][oc][ici] (ici fastest).
// ---------------------------------------------------------------------------
__global__ __launch_bounds__(256) void wprep_kernel(
    const float* __restrict__ w, short* __restrict__ W2hi, short* __restrict__ W2lo)
{
    __shared__ float lw[4608];
    const int t = threadIdx.x;
    const int oc = blockIdx.x;
    for (int i = t; i < 4608; i += 256) lw[i] = w[(long)oc * 4608 + i];
    __syncthreads();
    if (t < 144) {
        const int tap = t % 9, icb = t / 9;
        short hi[32], lo[32];
#pragma unroll
        for (int k = 0; k < 32; ++k)
            split_bf16(lw[(icb * 32 + k) * 9 + tap], hi[k], lo[k]);
        const long base = ((long)(tap * 16 + icb) * 512 + oc) * 32;
#pragma unroll
        for (int c4 = 0; c4 < 4; ++c4) {
            bf16x8 vh, vl;
#pragma unroll
            for (int j = 0; j < 8; ++j) { vh[j] = hi[c4 * 8 + j]; vl[j] = lo[c4 * 8 + j]; }
            *(bf16x8*)&W2hi[base + c4 * 8] = vh;
            *(bf16x8*)&W2lo[base + c4 * 8] = vl;
        }
    }
}

// ---------------------------------------------------------------------------
// conv3x3 split-bf16 MFMA, r6 geometry + reg-prefetch pipeline.
// Block tile: 128 px (4 rows) x 128 oc; grid (8,4,16) = 512 blocks (2/CU,
// LDS-pool-limited). 4 waves = 2(wo oc-half) x 2(wp px-half); per wave
// 64oc x 64px = 4x4 frags of 16x16x32. A=weights(m=oc), B=pixels(n=px).
// Pipeline per icb: {issue next-icb global loads -> regs} {compute from LDS}
// {barrier} {regs -> LDS} {barrier}. All staging descriptor arrays indexed by
// compile-time j only (stay in registers).
// ---------------------------------------------------------------------------
__global__ __launch_bounds__(256) void conv3x3_mfma(
    const short* __restrict__ XThi, const short* __restrict__ XTlo,
    const short* __restrict__ W2hi, const short* __restrict__ W2lo,
    const float* __restrict__ bias, float* __restrict__ y)
{
    __shared__ __align__(16) short Ah[6][34][40];
    __shared__ __align__(16) short Al[6][34][40];
    const int t = threadIdx.x;
    const int lane = t & 63, lg = lane >> 4, li = lane & 15;
    const int wv = t >> 6, wo = wv & 1, wp = wv >> 1;
    const int pt = blockIdx.x, ot = blockIdx.y, b = blockIdx.z;
    const int r0 = pt * 4;

    // staging chunk descriptors: 1632 chunks (2 arrays x 816), 7 per thread max
    long sbase[7];          // global short offset sans icb term
    int  doff[7];           // LDS short offset
    int  darr[7];           // 0=hi 1=lo
    bool live[7], inb[7];
#pragma unroll
    for (int j = 0; j < 7; ++j) {
        const int i = t + j * 256;
        live[j] = (i < 1632);
        const int ii = live[j] ? i : 0;
        const int arr = (ii >= 816) ? 1 : 0;
        const int pos = arr ? ii - 816 : ii;
        const int ch = pos & 3;
        const int xi = (pos >> 2) % 34;
        const int rs = (pos >> 2) / 34;
        const int g = r0 - 1 + rs, xg = xi - 1;
        inb[j] = live[j] && g >= 0 && g < HH && xg >= 0 && xg < WW;
        sbase[j] = (((long)b * 32 + g) * 32 + xg) * 512 + ch * 8;
        doff[j]  = (rs * 34 + xi) * 40 + ch * 8;
        darr[j]  = arr;
    }

    f32x4 acc[4][4];
#pragma unroll
    for (int i = 0; i < 4; ++i)
#pragma unroll
        for (int j = 0; j < 4; ++j) { f32x4 z = {0.f, 0.f, 0.f, 0.f}; acc[i][j] = z; }

    bf16x8 pref[7];
    // prologue: fetch + write icb 0
#pragma unroll
    for (int j = 0; j < 7; ++j) {
        bf16x8 v;
#pragma unroll
        for (int q = 0; q < 8; ++q) v[q] = 0;
        if (inb[j]) v = *(const bf16x8*)&(darr[j] ? XTlo : XThi)[sbase[j]];
        pref[j] = v;
    }
#pragma unroll
    for (int j = 0; j < 7; ++j)
        if (live[j])
            *(bf16x8*)&(darr[j] ? &Al[0][0][0] : &Ah[0][0][0])[doff[j]] = pref[j];
    __syncthreads();

    for (int icb = 0; icb < 16; ++icb) {
        // issue next-icb loads early; latency hides under this icb's MFMAs
        if (icb < 15) {
#pragma unroll
            for (int j = 0; j < 7; ++j) {
                bf16x8 v;
#pragma unroll
                for (int q = 0; q < 8; ++q) v[q] = 0;
                if (inb[j]) v = *(const bf16x8*)&(darr[j] ? XTlo : XThi)[sbase[j] + (icb + 1) * 32];
                pref[j] = v;
            }
        }
#pragma unroll
        for (int tap = 0; tap < 9; ++tap) {
            const int dy = tap / 3 - 1, dx = tap % 3 - 1;
            bf16x8 wh[4], wl[4];
#pragma unroll
            for (int of = 0; of < 4; ++of) {
                const long wb = ((long)(tap * 16 + icb) * 512
                                 + ot * 128 + wo * 64 + of * 16 + li) * 32 + lg * 8;
                wh[of] = *(const bf16x8*)&W2hi[wb];
                wl[of] = *(const bf16x8*)&W2lo[wb];
            }
#pragma unroll
            for (int pf = 0; pf < 4; ++pf) {
                const int rs = 2 * wp + (pf >> 1) + dy + 1;     // 0..5
                const int xs = (pf & 1) * 16 + li + dx + 1;     // 0..33
                const bf16x8 ph = *(const bf16x8*)&Ah[rs][xs][lg * 8];
                const bf16x8 pl = *(const bf16x8*)&Al[rs][xs][lg * 8];
#pragma unroll
                for (int of = 0; of < 4; ++of) {
                    acc[of][pf] = __builtin_amdgcn_mfma_f32_16x16x32_bf16(wh[of], ph, acc[of][pf], 0, 0, 0);
                    acc[of][pf] = __builtin_amdgcn_mfma_f32_16x16x32_bf16(wh[of], pl, acc[of][pf], 0, 0, 0);
                    acc[of][pf] = __builtin_amdgcn_mfma_f32_16x16x32_bf16(wl[of], ph, acc[of][pf], 0, 0, 0);
                }
            }
        }
        __syncthreads();
        if (icb < 15) {
#pragma unroll
            for (int j = 0; j < 7; ++j)
                if (live[j])
                    *(bf16x8*)&(darr[j] ? &Al[0][0][0] : &Ah[0][0][0])[doff[j]] = pref[j];
        }
        __syncthreads();
    }

#pragma unroll
    for (int of = 0; of < 4; ++of) {
        const int oc = ot * 128 + wo * 64 + of * 16 + lg * 4;
        const float4 b4 = *(const float4*)&bias[oc];
#pragma unroll
        for (int pf = 0; pf < 4; ++pf) {
            const int p = wp * 64 + pf * 16 + li;
            const int row = r0 + (p >> 5), xc = p & 31;
            float* yp = &y[((long)b * CCH + oc) * HWP + row * WW + xc];
#pragma unroll
            for (int r = 0; r < 4; ++r)
                yp[(long)r * HWP] = acc[of][pf][r] + (&b4.x)[r];
        }
    }
}

// ---------------------------------------------------------------------------
// gemmM: unified split-bf16 MFMA GEMM. A=[M][K], B=[N][K] (both k-contig).
//   AM/BM: 0 = fp32 global, split during LDS staging; 1 = pre-split bf16 pair
//   OM: 0 = fp32 C[M][N], val*alpha + bias[m] + skip  (skip may alias C)
//       1 = split-bf16 pair C[M][N] + bias[m]
//       2 = split-bf16 pair TRANSPOSED C[N][M] + bias[m] (contig 8B stores)
// Tile 128x128, BK=32, 4 waves (2x2), per-wave 4x4 frags of 16x16x32.
// ---------------------------------------------------------------------------
template<int AM, int BM, int OM>
__global__ __launch_bounds__(256) void gemmM(
    const void* __restrict__ Ah_, const void* __restrict__ Al_,
    const void* __restrict__ Bh_, const void* __restrict__ Bl_,
    void* Ch_, void* Cl_,
    const float* __restrict__ bias, const float* skip,
    const int M, const int N, const int K,
    const long sA, const long sB, const long sC, const float alpha)
{
    __shared__ __align__(16) short As[2][128][40];
    __shared__ __align__(16) short Bs[2][128][40];
    const int t = threadIdx.x;
    const int li = t & 15, lg = (t >> 4) & 3;
    const int wv = t >> 6, wn = wv & 1, wm = wv >> 1;
    const int n0 = blockIdx.x * 128, m0 = blockIdx.y * 128;
    const long z = blockIdx.z;

    f32x4 acc[4][4];
#pragma unroll
    for (int i = 0; i < 4; ++i)
#pragma unroll
        for (int j = 0; j < 4; ++j) { f32x4 zz = {0.f, 0.f, 0.f, 0.f}; acc[i][j] = zz; }

    for (int k0 = 0; k0 < K; k0 += 32) {
        __syncthreads();
        // ---- stage A tile (128 m x 32 k) ----
        if (AM == 0) {
            const float* Af = (const float*)Ah_ + z * sA;
            const int m = t >> 1, kh = (t & 1) * 16;
            const float* src = &Af[(long)(m0 + m) * K + k0 + kh];
            short h[16], l[16];
#pragma unroll
            for (int q = 0; q < 4; ++q) {
                const float4 f = *(const float4*)&src[q * 4];
#pragma unroll
                for (int j = 0; j < 4; ++j) split_bf16((&f.x)[j], h[q * 4 + j], l[q * 4 + j]);
            }
            *(bf16x8*)&As[0][m][kh]     = *(bf16x8*)&h[0];
            *(bf16x8*)&As[0][m][kh + 8] = *(bf16x8*)&h[8];
            *(bf16x8*)&As[1][m][kh]     = *(bf16x8*)&l[0];
            *(bf16x8*)&As[1][m][kh + 8] = *(bf16x8*)&l[8];
        } else {
            const int m = t & 127, arr = t >> 7;
            const short* src = ((arr ? (const short*)Al_ : (const short*)Ah_) + z * sA)
                               + (long)(m0 + m) * K + k0;
#pragma unroll
            for (int q = 0; q < 4; ++q)
                *(bf16x8*)&As[arr][m][q * 8] = *(const bf16x8*)&src[q * 8];
        }
        // ---- stage B tile (128 n x 32 k) ----
        if (BM == 0) {
            const float* Bf = (const float*)Bh_ + z * sB;
            const int n = t >> 1, kh = (t & 1) * 16;
            const float* src = &Bf[(long)(n0 + n) * K + k0 + kh];
            short h[16], l[16];
#pragma unroll
            for (int q = 0; q < 4; ++q) {
                const float4 f = *(const float4*)&src[q * 4];
#pragma unroll
                for (int j = 0; j < 4; ++j) split_bf16((&f.x)[j], h[q * 4 + j], l[q * 4 + j]);
            }
            *(bf16x8*)&Bs[0][n][kh]     = *(bf16x8*)&h[0];
            *(bf16x8*)&Bs[0][n][kh + 8] = *(bf16x8*)&h[8];
            *(bf16x8*)&Bs[1][n][kh]     = *(bf16x8*)&l[0];
            *(bf16x8*)&Bs[1][n][kh + 8] = *(bf16x8*)&l[8];
        } else {
            const int n = t & 127, arr = t >> 7;
            const short* src = ((arr ? (const short*)Bl_ : (const short*)Bh_) + z * sB)
                               + (long)(n0 + n) * K + k0;
#pragma unroll
            for (int q = 0; q < 4; ++q)
                *(bf16x8*)&Bs[arr][n][q * 8] = *(const bf16x8*)&src[q * 8];
        }
        __syncthreads();

        bf16x8 ah[4], al[4], bh[4], bl[4];
#pragma unroll
        for (int f = 0; f < 4; ++f) {
            const int ra = wm * 64 + f * 16 + li;
            ah[f] = *(const bf16x8*)&As[0][ra][lg * 8];
            al[f] = *(const bf16x8*)&As[1][ra][lg * 8];
            const int rb = wn * 64 + f * 16 + li;
            bh[f] = *(const bf16x8*)&Bs[0][rb][lg * 8];
            bl[f] = *(const bf16x8*)&Bs[1][rb][lg * 8];
        }
#pragma unroll
        for (int fm = 0; fm < 4; ++fm)
#pragma unroll
            for (int fn = 0; fn < 4; ++fn) {
                acc[fm][fn] = __builtin_amdgcn_mfma_f32_16x16x32_bf16(ah[fm], bh[fn], acc[fm][fn], 0, 0, 0);
                acc[fm][fn] = __builtin_amdgcn_mfma_f32_16x16x32_bf16(ah[fm], bl[fn], acc[fm][fn], 0, 0, 0);
                acc[fm][fn] = __builtin_amdgcn_mfma_f32_16x16x32_bf16(al[fm], bh[fn], acc[fm][fn], 0, 0, 0);
            }
    }

    // ---- epilogue ----
#pragma unroll
    for (int fm = 0; fm < 4; ++fm) {
        const int gmb = m0 + wm * 64 + fm * 16 + lg * 4;
#pragma unroll
        for (int fn = 0; fn < 4; ++fn) {
            const int gn = n0 + wn * 64 + fn * 16 + li;
            if (OM == 0) {
                float* C = (float*)Ch_ + z * sC;
                const float* S = skip ? skip + z * sC : (const float*)0;
#pragma unroll
                for (int r = 0; r < 4; ++r) {
                    const int gm = gmb + r;
                    float v = acc[fm][fn][r] * alpha + (bias ? bias[gm] : 0.f);
                    const long off = (long)gm * N + gn;
                    if (S) v += S[off];
                    C[off] = v;
                }
            } else if (OM == 1) {
                short* Ch = (short*)Ch_ + z * sC;
                short* Cl = (short*)Cl_ + z * sC;
#pragma unroll
                for (int r = 0; r < 4; ++r) {
                    const int gm = gmb + r;
                    float v = acc[fm][fn][r] + (bias ? bias[gm] : 0.f);
                    short h, l; split_bf16(v, h, l);
                    const long off = (long)gm * N + gn;
                    Ch[off] = h; Cl[off] = l;
                }
            } else {
                short* Ch = (short*)Ch_ + z * sC;
                short* Cl = (short*)Cl_ + z * sC;
                s16x4 hv, lv;
#pragma unroll
                for (int r = 0; r < 4; ++r) {
                    float v = acc[fm][fn][r] + (bias ? bias[gmb + r] : 0.f);
                    short h, l; split_bf16(v, h, l);
                    hv[r] = h; lv[r] = l;
                }
                const long off = (long)gn * M + gmb;
                *(s16x4*)&Ch[off] = hv;
                *(s16x4*)&Cl[off] = lv;
            }
        }
    }
}

// ---------------------------------------------------------------------------
// GN stat helper (per-(b,group) block, 256 thr; 16384 floats in registers).
// ---------------------------------------------------------------------------
static __device__ __forceinline__ void gn_stats(
    const float* in, long base, int t, float4 (&v)[16], float& mean, float& inv)
{
    float sum = 0.f, ssq = 0.f;
#pragma unroll
    for (int i = 0; i < 16; ++i) {
        v[i] = *(const float4*)&in[base + (long)(t + 256 * i) * 4];
        sum += v[i].x + v[i].y + v[i].z + v[i].w;
        ssq += v[i].x * v[i].x + v[i].y * v[i].y + v[i].z * v[i].z + v[i].w * v[i].w;
    }
#pragma unroll
    for (int off = 32; off > 0; off >>= 1) {
        sum += __shfl_xor(sum, off);
        ssq += __shfl_xor(ssq, off);
    }
    __shared__ float redS[4], redQ[4];
    const int wid = t >> 6;
    if ((t & 63) == 0) { redS[wid] = sum; redQ[wid] = ssq; }
    __syncthreads();
    sum = redS[0] + redS[1] + redS[2] + redS[3];
    ssq = redQ[0] + redQ[1] + redQ[2] + redQ[3];
    mean = sum * (1.f / 16384.f);
    const float var = ssq * (1.f / 16384.f) - mean * mean;
    inv = rsqrtf(var + GN_EPS);
}

// GroupNorm (+SiLU/+skip), fp32 out. In-place safe. flags: bit0 silu, bit1 skip
__global__ __launch_bounds__(256) void gn_kernel(
    const float* in, const float* __restrict__ gamma,
    const float* __restrict__ beta, const float* __restrict__ skip,
    float* out, const int flags)
{
    const int t = threadIdx.x;
    const int b = blockIdx.x >> 5;
    const int g = blockIdx.x & 31;
    const long base = ((long)b * CCH + g * CPG) * HWP;
    float4 v[16];
    float mean, inv;
    gn_stats(in, base, t, v, mean, inv);
#pragma unroll
    for (int i = 0; i < 16; ++i) {
        const float ga = gamma[g * CPG + i];
        const float be = beta[g * CPG + i];
        float r[4] = { v[i].x, v[i].y, v[i].z, v[i].w };
        float4 o;
        float* op = &o.x;
#pragma unroll
        for (int c = 0; c < 4; ++c) {
            float val = (r[c] - mean) * inv * ga + be;
            if (flags & 1) val = val / (1.f + expf(-val));
            op[c] = val;
        }
        if (flags & 2) {
            const float4 s4 = *(const float4*)&skip[base + (long)(t + 256 * i) * 4];
            o.x += s4.x; o.y += s4.y; o.z += s4.z; o.w += s4.w;
        }
        *(float4*)&out[base + (long)(t + 256 * i) * 4] = o;
    }
}

// GN -> split-bf16 transposed [b][px][c] pair, optional SiLU.
template<int SILU>
__global__ __launch_bounds__(256) void gn_tsplit_k(
    const float* __restrict__ in, const float* __restrict__ gamma,
    const float* __restrict__ beta, short* __restrict__ Th, short* __restrict__ Tl)
{
    const int t = threadIdx.x;
    const int b = blockIdx.x >> 5;
    const int g = blockIdx.x & 31;
    const long base = ((long)b * CCH + g * CPG) * HWP;
    float4 v[16];
    float mean, inv;
    gn_stats(in, base, t, v, mean, inv);
#pragma unroll
    for (int cc = 0; cc < 4; ++cc) {
        short h[16], l[16];
#pragma unroll
        for (int i = 0; i < 16; ++i) {
            float val = ((&v[i].x)[cc] - mean) * inv * gamma[g * CPG + i] + beta[g * CPG + i];
            if (SILU) val = val / (1.f + expf(-val));
            split_bf16(val, h[i], l[i]);
        }
        const long o = ((long)b * HWP + (t * 4 + cc)) * CCH + g * CPG;
        *(bf16x8*)&Th[o]     = *(bf16x8*)&h[0];
        *(bf16x8*)&Th[o + 8] = *(bf16x8*)&h[8];
        *(bf16x8*)&Tl[o]     = *(bf16x8*)&l[0];
        *(bf16x8*)&Tl[o + 8] = *(bf16x8*)&l[8];
    }
}

// ---------------------------------------------------------------------------
__global__ __launch_bounds__(256) void softmax_kernel(float* __restrict__ s)
{
    float* p = s + (long)blockIdx.x * HWP;
    const int t = threadIdx.x;
    float4 v = *(float4*)&p[t * 4];
    float mx = fmaxf(fmaxf(v.x, v.y), fmaxf(v.z, v.w));
#pragma unroll
    for (int off = 32; off > 0; off >>= 1) mx = fmaxf(mx, __shfl_xor(mx, off));
    __shared__ float redm[4], reds[4];
    const int wid = t >> 6;
    if ((t & 63) == 0) redm[wid] = mx;
    __syncthreads();
    mx = fmaxf(fmaxf(redm[0], redm[1]), fmaxf(redm[2], redm[3]));
    float4 e;
    e.x = expf(v.x - mx); e.y = expf(v.y - mx);
    e.z = expf(v.z - mx); e.w = expf(v.w - mx);
    float sm = e.x + e.y + e.z + e.w;
#pragma unroll
    for (int off = 32; off > 0; off >>= 1) sm += __shfl_xor(sm, off);
    if ((t & 63) == 0) reds[wid] = sm;
    __syncthreads();
    sm = reds[0] + reds[1] + reds[2] + reds[3];
    const float r = 1.f / sm;
    e.x *= r; e.y *= r; e.z *= r; e.w *= r;
    *(float4*)&p[t * 4] = e;
}

// ---------------------------------------------------------------------------
// fp32 fallbacks (audited baseline) for the tiny-workspace tier
// ---------------------------------------------------------------------------
#define OCT 8
#define ICT 4
__global__ __launch_bounds__(256) void conv3x3_kernel(
    const float* __restrict__ x, const float* __restrict__ w,
    const float* __restrict__ bias, float* __restrict__ y)
{
    __shared__ float lds[ICT][34][36];
    const int t = threadIdx.x;
    const int oc0 = blockIdx.x * OCT;
    const int b = blockIdx.y;
    const int row = t >> 3;
    const int col = (t & 7) << 2;
    float acc[OCT][4];
#pragma unroll
    for (int o = 0; o < OCT; ++o)
#pragma unroll
        for (int p = 0; p < 4; ++p) acc[o][p] = 0.f;
    const float* xb = x + (long)b * CCH * HWP;
    for (int ic0 = 0; ic0 < CCH; ic0 += ICT) {
        __syncthreads();
#pragma unroll
        for (int pl = 0; pl < ICT; ++pl) {
            for (int i = t; i < 34 * 34; i += 256) {
                const int r = i / 34, cc = i - r * 34;
                const int gy = r - 1, gx = cc - 1;
                float v = 0.f;
                if (gy >= 0 && gy < HH && gx >= 0 && gx < WW)
                    v = xb[(long)(ic0 + pl) * HWP + gy * WW + gx];
                lds[pl][r][cc] = v;
            }
        }
        __syncthreads();
#pragma unroll
        for (int ic = 0; ic < ICT; ++ic) {
#pragma unroll
            for (int dy = 0; dy < 3; ++dy) {
                float in6[6];
#pragma unroll
                for (int j = 0; j < 6; ++j) in6[j] = lds[ic][row + dy][col + j];
#pragma unroll
                for (int dx = 0; dx < 3; ++dx) {
#pragma unroll
                    for (int o = 0; o < OCT; ++o) {
                        const float ww = w[((long)(oc0 + o) * CCH + ic0 + ic) * 9 + dy * 3 + dx];
#pragma unroll
                        for (int p = 0; p < 4; ++p)
                            acc[o][p] = fmaf(ww, in6[p + dx], acc[o][p]);
                    }
                }
            }
        }
    }
#pragma unroll
    for (int o = 0; o < OCT; ++o) {
        const float bv = bias[oc0 + o];
        float4 o4;
        o4.x = acc[o][0] + bv; o4.y = acc[o][1] + bv;
        o4.z = acc[o][2] + bv; o4.w = acc[o][3] + bv;
        *(float4*)&y[((long)(b * CCH + oc0 + o)) * HWP + row * WW + col] = o4;
    }
}

template<int AT, int BT>
__global__ __launch_bounds__(256) void gemm128(
    const float* __restrict__ A, const float* __restrict__ B,
    float* C, const float* __restrict__ bias, const float* skip,
    const int M, const int N, const int K,
    const long sA, const long sB, const long sC, const float alpha)
{
    __shared__ float as[16][132];
    __shared__ float bs[16][132];
    const int t = threadIdx.x;
    const int n0 = blockIdx.x * 128;
    const int m0 = blockIdx.y * 128;
    const float* Ap = A + (long)blockIdx.z * sA;
    const float* Bp = B + (long)blockIdx.z * sB;
    float* Cp = C + (long)blockIdx.z * sC;
    const float* Sp = skip ? skip + (long)blockIdx.z * sC : (const float*)0;
    const int tm = (t & 15) * 4;
    const int tn = (t >> 4) * 4;
    float acc[8][8];
#pragma unroll
    for (int i = 0; i < 8; ++i)
#pragma unroll
        for (int j = 0; j < 8; ++j) acc[i][j] = 0.f;
    for (int k0 = 0; k0 < K; k0 += 16) {
        __syncthreads();
        if (AT == 0) {
            const int m = t & 127;
            const int kg = (t >> 7) * 8;
            const float4 a0 = *(const float4*)&Ap[(long)(m0 + m) * K + k0 + kg];
            const float4 a1 = *(const float4*)&Ap[(long)(m0 + m) * K + k0 + kg + 4];
            as[kg + 0][m] = a0.x; as[kg + 1][m] = a0.y;
            as[kg + 2][m] = a0.z; as[kg + 3][m] = a0.w;
            as[kg + 4][m] = a1.x; as[kg + 5][m] = a1.y;
            as[kg + 6][m] = a1.z; as[kg + 7][m] = a1.w;
        } else {
            const int kk = t >> 4;
            const int mm = (t & 15) * 4;
            *(float4*)&as[kk][mm]      = *(const float4*)&Ap[(long)(k0 + kk) * M + m0 + mm];
            *(float4*)&as[kk][mm + 64] = *(const float4*)&Ap[(long)(k0 + kk) * M + m0 + mm + 64];
        }
        if (BT == 0) {
            const int kk = t >> 4;
            const int nn = (t & 15) * 4;
            *(float4*)&bs[kk][nn]      = *(const float4*)&Bp[(long)(k0 + kk) * N + n0 + nn];
            *(float4*)&bs[kk][nn + 64] = *(const float4*)&Bp[(long)(k0 + kk) * N + n0 + nn + 64];
        } else {
            const int n = t & 127;
            const int kg = (t >> 7) * 8;
            const float4 b0 = *(const float4*)&Bp[(long)(n0 + n) * K + k0 + kg];
            const float4 b1 = *(const float4*)&Bp[(long)(n0 + n) * K + k0 + kg + 4];
            bs[kg + 0][n] = b0.x; bs[kg + 1][n] = b0.y;
            bs[kg + 2][n] = b0.z; bs[kg + 3][n] = b0.w;
            bs[kg + 4][n] = b1.x; bs[kg + 5][n] = b1.y;
            bs[kg + 6][n] = b1.z; bs[kg + 7][n] = b1.w;
        }
        __syncthreads();
#pragma unroll
        for (int kk = 0; kk < 16; ++kk) {
            float av[8], bv[8];
            *(float4*)&av[0] = *(const float4*)&as[kk][tm];
            *(float4*)&av[4] = *(const float4*)&as[kk][tm + 64];
            *(float4*)&bv[0] = *(const float4*)&bs[kk][tn];
            *(float4*)&bv[4] = *(const float4*)&bs[kk][tn + 64];
#pragma unroll
            for (int i = 0; i < 8; ++i)
#pragma unroll
                for (int j = 0; j < 8; ++j)
                    acc[i][j] = fmaf(av[i], bv[j], acc[i][j]);
        }
    }
#pragma unroll
    for (int i = 0; i < 8; ++i) {
        const int ri = m0 + ((i < 4) ? (tm + i) : (64 + tm + i - 4));
        const float bv = bias ? bias[ri] : 0.f;
#pragma unroll
        for (int jh = 0; jh < 2; ++jh) {
            const int cj = n0 + ((jh == 0) ? tn : (64 + tn));
            const long off = (long)ri * N + cj;
            float4 o;
            float* op = &o.x;
#pragma unroll
            for (int j = 0; j < 4; ++j) op[j] = acc[i][jh * 4 + j] * alpha + bv;
            if (Sp) {
                const float4 s4 = *(const float4*)&Sp[off];
                o.x += s4.x; o.y += s4.y; o.z += s4.z; o.w += s4.w;
            }
            *(float4*)&Cp[off] = o;
        }
    }
}

// ---------------------------------------------------------------------------
extern "C" void kernel_launch(void* const* d_in, const int* in_sizes, int n_in,
                              void* d_out, int out_size, void* d_ws, size_t ws_size,
                              hipStream_t stream)
{
    const float* x      = (const float*)d_in[0];
    const float* r1_c1w = (const float*)d_in[1];
    const float* r1_c1b = (const float*)d_in[2];
    const float* r1_g1  = (const float*)d_in[3];
    const float* r1_b1  = (const float*)d_in[4];
    const float* r1_c2w = (const float*)d_in[5];
    const float* r1_c2b = (const float*)d_in[6];
    const float* r1_g2  = (const float*)d_in[7];
    const float* r1_b2  = (const float*)d_in[8];
    const float* a_g    = (const float*)d_in[9];
    const float* a_b    = (const float*)d_in[10];
    const float* a_qw   = (const float*)d_in[11];
    const float* a_qb   = (const float*)d_in[12];
    const float* a_kw   = (const float*)d_in[13];
    const float* a_kb   = (const float*)d_in[14];
    const float* a_vw   = (const float*)d_in[15];
    const float* a_vb   = (const float*)d_in[16];
    const float* a_pw   = (const float*)d_in[17];
    const float* a_pb   = (const float*)d_in[18];
    const float* r2_c1w = (const float*)d_in[19];
    const float* r2_c1b = (const float*)d_in[20];
    const float* r2_g1  = (const float*)d_in[21];
    const float* r2_b1  = (const float*)d_in[22];
    const float* r2_c2w = (const float*)d_in[23];
    const float* r2_c2b = (const float*)d_in[24];
    const float* r2_g2  = (const float*)d_in[25];
    const float* r2_b2  = (const float*)d_in[26];

    const long NB1   = (long)CCH * HWP;          // 524288
    const long NBUF  = (long)BATCH * NB1;        // 8.39M (33.5 MB fp32)
    const long SB1   = (long)HWP * HWP;
    const long SFULL = (long)BATCH * SB1;
    const long WSPL  = (long)9 * 16 * 512 * 32;  // 2.36M shorts per weight array

    float* ws   = (float*)d_ws;
    float* bufA = ws;
    float* bufB = ws + NBUF;
    float* out  = (float*)d_out;

    // Shared region R after bufA/bufB: conv scratch and attention scratch
    // alias each other (disjoint live ranges, verified phase order).
    short* R    = (short*)(ws + 2 * NBUF);
    short* XThi = R;                 // conv phase
    short* XTlo = R + NBUF;
    short* W2hi = R + 2 * NBUF;
    short* W2lo = W2hi + WSPL;
    short* hnTh = R;                 // attention phase (aliases XT; XT dead)
    short* hnTl = R + NBUF;
    short* Qth  = R + 2 * NBUF;      // aliases W2 + beyond (W2 dead)
    short* Qtl  = R + 3 * NBUF;
    short* Kth  = R + 4 * NBUF;
    short* Ktl  = R + 5 * NBUF;
    short* hTh  = Qth;               // Qt dead after S
    short* hTl  = Qtl;
    float* Sf   = (float*)(R + 6 * NBUF);
    short* Vh   = (short*)d_out;     // V pair lives in d_out (dead at end)
    short* Vl   = Vh + NBUF;

    // tier thresholds (bytes)
    const size_t t1 = (size_t)20 * NBUF + (size_t)4 * SFULL;           // ~235 MB
    const size_t t2 = (size_t)20 * NBUF + (size_t)4 * SB1;             // ~172 MB
    const size_t t3 = (size_t)8 * NBUF + (size_t)(2 * NBUF + 2 * WSPL) * 2
                    + (size_t)(3 * NB1 + SB1) * 4;                     // ~121 MB
    const int tier = (ws_size >= t1) ? 1 : (ws_size >= t2) ? 2
                   : (ws_size >= t3) ? 3 : 4;

    const float scale = 0.04419417382415922f;    // 512^-0.5

    const dim3 gConvM(HWP / 128, CCH / 128, BATCH);  // (8,4,16) — r6 geometry
    const dim3 gXS(HH, BATCH);
    const dim3 gConvF(CCH / OCT, BATCH);
    const dim3 gGN(BATCH * NGRP);
    const dim3 gProj(HWP / 128, CCH / 128, BATCH);   // (8,4,16) M=512 N=1024
    const dim3 gS(HWP / 128, HWP / 128, BATCH);      // (8,8,16)
    const dim3 gSb(HWP / 128, HWP / 128, 1);
    const dim3 gPVb(HWP / 128, CCH / 128, 1);
    const dim3 g1x1b(HWP / 128, CCH / 128, 1);

    // ---- ResNet block 1 ----
    if (tier <= 3) {
        xsplit_kernel<<<gXS, 256, 0, stream>>>(x, XThi, XTlo);
        wprep_kernel<<<CCH, 256, 0, stream>>>(r1_c1w, W2hi, W2lo);
        conv3x3_mfma<<<gConvM, 256, 0, stream>>>(XThi, XTlo, W2hi, W2lo, r1_c1b, bufA);
        gn_tsplit_k<1><<<gGN, 256, 0, stream>>>(bufA, r1_g1, r1_b1, XThi, XTlo);
        wprep_kernel<<<CCH, 256, 0, stream>>>(r1_c2w, W2hi, W2lo);
        conv3x3_mfma<<<gConvM, 256, 0, stream>>>(XThi, XTlo, W2hi, W2lo, r1_c2b, bufB);
    } else {
        conv3x3_kernel<<<gConvF, 256, 0, stream>>>(x, r1_c1w, r1_c1b, bufA);
        gn_kernel<<<gGN, 256, 0, stream>>>(bufA, r1_g1, r1_b1, nullptr, bufA, 1);
        conv3x3_kernel<<<gConvF, 256, 0, stream>>>(bufA, r1_c2w, r1_c2b, bufB);
    }
    gn_kernel<<<gGN, 256, 0, stream>>>(bufB, r1_g2, r1_b2, x, bufB, 3);   // bufB = x1

    // ---- Attention ----
    if (tier <= 2) {
        gn_tsplit_k<0><<<gGN, 256, 0, stream>>>(bufB, a_g, a_b, hnTh, hnTl);
        gemmM<0, 1, 2><<<gProj, 256, 0, stream>>>(a_qw, nullptr, hnTh, hnTl,
            Qth, Qtl, a_qb, nullptr, CCH, HWP, CCH, 0, NB1, NB1, 1.f);
        gemmM<0, 1, 2><<<gProj, 256, 0, stream>>>(a_kw, nullptr, hnTh, hnTl,
            Kth, Ktl, a_kb, nullptr, CCH, HWP, CCH, 0, NB1, NB1, 1.f);
        gemmM<0, 1, 1><<<gProj, 256, 0, stream>>>(a_vw, nullptr, hnTh, hnTl,
            Vh, Vl, a_vb, nullptr, CCH, HWP, CCH, 0, NB1, NB1, 1.f);
        if (tier == 1) {
            gemmM<1, 1, 0><<<gS, 256, 0, stream>>>(Qth, Qtl, Kth, Ktl,
                Sf, nullptr, nullptr, nullptr, HWP, HWP, CCH, NB1, NB1, SB1, scale);
            softmax_kernel<<<BATCH * HWP, 256, 0, stream>>>(Sf);
            gemmM<1, 0, 2><<<gProj, 256, 0, stream>>>(Vh, Vl, Sf, nullptr,
                hTh, hTl, nullptr, nullptr, CCH, HWP, HWP, NB1, SB1, NB1, 1.f);
        } else {
            for (int b = 0; b < BATCH; ++b) {
                gemmM<1, 1, 0><<<gSb, 256, 0, stream>>>(Qth + b * NB1, Qtl + b * NB1,
                    Kth + b * NB1, Ktl + b * NB1, Sf, nullptr, nullptr, nullptr,
                    HWP, HWP, CCH, 0, 0, 0, scale);
                softmax_kernel<<<HWP, 256, 0, stream>>>(Sf);
                gemmM<1, 0, 2><<<gPVb, 256, 0, stream>>>(Vh + b * NB1, Vl + b * NB1,
                    Sf, nullptr, hTh + b * NB1, hTl + b * NB1, nullptr, nullptr,
                    CCH, HWP, HWP, 0, 0, 0, 1.f);
            }
        }
        // x2 = x1 + pw*hT + pb (in-place skip on bufB)
        gemmM<0, 1, 0><<<gProj, 256, 0, stream>>>(a_pw, nullptr, hTh, hTl,
            bufB, nullptr, a_pb, bufB, CCH, HWP, CCH, 0, NB1, NB1, 1.f);
    } else {
        gn_kernel<<<gGN, 256, 0, stream>>>(bufB, a_g, a_b, nullptr, bufA, 0);
        float* qq = (tier == 3) ? (float*)(R + 2 * NBUF + 2 * WSPL) : (float*)R;
        float* kk = qq + NB1;
        float* vv = kk + NB1;
        float* ssb = vv + NB1;
        const dim3 gQKb(HWP / 128, HWP / 128, 1);
        for (int b = 0; b < BATCH; ++b) {
            const float* hnb = bufA + (long)b * NB1;
            gemm128<0, 0><<<g1x1b, 256, 0, stream>>>(a_qw, hnb, qq, a_qb, nullptr,
                                                     CCH, HWP, CCH, 0, 0, 0, 1.f);
            gemm128<0, 0><<<g1x1b, 256, 0, stream>>>(a_kw, hnb, kk, a_kb, nullptr,
                                                     CCH, HWP, CCH, 0, 0, 0, 1.f);
            gemm128<0, 0><<<g1x1b, 256, 0, stream>>>(a_vw, hnb, vv, a_vb, nullptr,
                                                     CCH, HWP, CCH, 0, 0, 0, 1.f);
            gemm128<1, 0><<<gQKb, 256, 0, stream>>>(qq, kk, ssb, nullptr, nullptr,
                                                    HWP, HWP, CCH, 0, 0, 0, scale);
            softmax_kernel<<<HWP, 256, 0, stream>>>(ssb);
            gemm128<0, 1><<<g1x1b, 256, 0, stream>>>(vv, ssb, qq, nullptr, nullptr,
                                                     CCH, HWP, HWP, 0, 0, 0, 1.f);
            gemm128<0, 0><<<g1x1b, 256, 0, stream>>>(a_pw, qq, bufB + (long)b * NB1,
                                                     a_pb, bufB + (long)b * NB1,
                                                     CCH, HWP, CCH, 0, 0, 0, 1.f);
        }
    }

    // ---- ResNet block 2 ----
    if (tier <= 3) {
        xsplit_kernel<<<gXS, 256, 0, stream>>>(bufB, XThi, XTlo);
        wprep_kernel<<<CCH, 256, 0, stream>>>(r2_c1w, W2hi, W2lo);
        conv3x3_mfma<<<gConvM, 256, 0, stream>>>(XThi, XTlo, W2hi, W2lo, r2_c1b, bufA);
        gn_tsplit_k<1><<<gGN, 256, 0, stream>>>(bufA, r2_g1, r2_b1, XThi, XTlo);
        wprep_kernel<<<CCH, 256, 0, stream>>>(r2_c2w, W2hi, W2lo);
        conv3x3_mfma<<<gConvM, 256, 0, stream>>>(XThi, XTlo, W2hi, W2lo, r2_c2b, bufA);
    } else {
        conv3x3_kernel<<<gConvF, 256, 0, stream>>>(bufB, r2_c1w, r2_c1b, bufA);
        gn_kernel<<<gGN, 256, 0, stream>>>(bufA, r2_g1, r2_b1, nullptr, bufA, 1);
        conv3x3_kernel<<<gConvF, 256, 0, stream>>>(bufA, r2_c2w, r2_c2b, bufA);
    }
    gn_kernel<<<gGN, 256, 0, stream>>>(bufA, r2_g2, r2_b2, bufB, out, 3);
}